// Round 5
// baseline (507.459 us; speedup 1.0000x reference)
//
#include <hip/hip_runtime.h>
#include <cmath>

#define NNODES 60000
#define DDIM   200
#define NCLS   250

constexpr int XP = 208;    // pitch (shorts) of LDS activation buffers
constexpr int SH_TOT = 3 * 64 * XP + 64;   // bufA | bufB | bufX | tail pad

typedef float  f32x4   __attribute__((ext_vector_type(4)));
typedef short  short8  __attribute__((ext_vector_type(8)));
typedef short  short4v __attribute__((ext_vector_type(4)));

// ---- ws layout (bf16 elems). All mats [256][Kpad], rows>=ncols zero, k>=Kreal zero.
constexpr int W_P1  = 0;              // [256][608]
constexpr int W_P2A = 155648;         // [256][224] each below
constexpr int W_P2B = 212992;
constexpr int W_FX  = 270336;
constexpr int W_FH  = 327680;
constexpr int W_IX  = 385024;
constexpr int W_IH  = 442368;
constexpr int W_UX  = 499712;
constexpr int W_UH  = 557056;
constexpr int W_OX  = 614400;
constexpr int W_OH  = 671744;
constexpr int W_FC2 = 729088;
constexpr int W_TOTAL_ELEMS = 786432;                 // *2 = 1,572,864 bytes
constexpr size_t W_TOTAL_BYTES = (size_t)W_TOTAL_ELEMS * 2;

__device__ __forceinline__ short f2b(float f) {      // manual RNE (cold paths)
    union { float f; unsigned u; } x; x.f = f;
    unsigned r = (x.u + 0x7FFFu + ((x.u >> 16) & 1u)) >> 16;
    return (short)r;
}
__device__ __forceinline__ unsigned cvtpk(float lo, float hi) {
    unsigned r; asm("v_cvt_pk_bf16_f32 %0, %1, %2" : "=v"(r) : "v"(lo), "v"(hi));
    return r;
}
__device__ __forceinline__ short f2b1(float f) { return (short)(cvtpk(f, f) & 0xffffu); }
__device__ __forceinline__ float b2f(short s) {
    union { unsigned u; float f; } x; x.u = ((unsigned)(unsigned short)s) << 16;
    return x.f;
}
__device__ __forceinline__ float b2f_lo(unsigned u) { return b2f((short)(u & 0xffffu)); }
__device__ __forceinline__ float b2f_hi(unsigned u) { return b2f((short)(u >> 16)); }
__device__ __forceinline__ float sgm(float x)  { return 1.0f / (1.0f + __expf(-x)); }
__device__ __forceinline__ float tanh_fast(float x) { return 1.0f - 2.0f / (__expf(2.0f * x) + 1.0f); }

// ================= weight prepass: fp32 -> bf16 padded mats in ws =================
__global__ void wprep(const float* __restrict__ p1w, const float* __restrict__ p2w,
                      const float* __restrict__ fxw, const float* __restrict__ fhw,
                      const float* __restrict__ ixw, const float* __restrict__ ihw,
                      const float* __restrict__ uxw, const float* __restrict__ uhw,
                      const float* __restrict__ oxw, const float* __restrict__ ohw,
                      const float* __restrict__ fc2w, short* __restrict__ ws)
{
    int i = blockIdx.x * 256 + threadIdx.x;
    if (i >= W_TOTAL_ELEMS) return;
    float v = 0.0f;
    if (i < W_P2A) {                       // p1: [256][608], src 200x600
        int n = i / 608, k = i % 608;
        if (n < 200 && k < 600) v = p1w[n * 600 + k];
        ws[i] = f2b(v); return;
    }
    int j = i - W_P2A;
    int m = j / 57344, rem = j % 57344;
    int n = rem / 224, k = rem % 224;
    const float* src; int stride = 200, off = 0, ncols = 200;
    switch (m) {
        case 0:  src = p2w; stride = 400; break;
        case 1:  src = p2w; stride = 400; off = 200; break;
        case 2:  src = fxw; break;
        case 3:  src = fhw; break;
        case 4:  src = ixw; break;
        case 5:  src = ihw; break;
        case 6:  src = uxw; break;
        case 7:  src = uhw; break;
        case 8:  src = oxw; break;
        case 9:  src = ohw; break;
        default: src = fc2w; ncols = 250; break;
    }
    if (n < ncols && k < 200) v = src[n * stride + off + k];
    ws[i] = f2b(v);
}

// ================= fragment loads =================
__device__ __forceinline__ short8 ldw_g(const short* __restrict__ mat, int Kpad, int n, int k) {
    return *(const short8*)(mat + (long)n * Kpad + k);
}
__device__ __forceinline__ short8 lda_g32(const float* __restrict__ p) {
    float4 f0 = *(const float4*)p;
    float4 f1 = *(const float4*)(p + 4);
    unsigned u0 = cvtpk(f0.x, f0.y), u1 = cvtpk(f0.z, f0.w);
    unsigned u2 = cvtpk(f1.x, f1.y), u3 = cvtpk(f1.z, f1.w);
    union { unsigned u[4]; short8 s; } c;
    c.u[0] = u0; c.u[1] = u1; c.u[2] = u2; c.u[3] = u3;
    return c.s;
}
__device__ __forceinline__ short8 lda_l(const short* __restrict__ p) {
    return *(const short8*)p;
}

// ---- GEMM pass, A from global fp32 (chh). 1-deep prefetch pipeline, no barriers. ----
template<int KT>
__device__ __forceinline__ void pass_ga(f32x4 (&acc)[2][8],
    const float* __restrict__ a0p, const float* __restrict__ a1p, int Kreal,
    const short* __restrict__ wp, int Kpad, int nbase, int lg)
{
    const int kb = lg * 8;
    short8 a0 = lda_g32(a0p + kb);
    short8 a1 = lda_g32(a1p + kb);
    short8 w[7];
    #pragma unroll
    for (int ni = 0; ni < 7; ++ni) w[ni] = ldw_g(wp, Kpad, nbase + ni * 16, kb);
    #pragma unroll 1
    for (int t = 0; t < KT; ++t) {
        const int kn = (t + 1) * 32 + kb;
        const int ka = (t + 1 < KT) ? ((kn < Kreal) ? kn : 0) : 0;
        const int kw = (t + 1 < KT) ? kn : 0;
        short8 na0 = lda_g32(a0p + ka);
        short8 na1 = lda_g32(a1p + ka);
        short8 nw[7];
        #pragma unroll
        for (int ni = 0; ni < 7; ++ni) nw[ni] = ldw_g(wp, Kpad, nbase + ni * 16, kw);
        #pragma unroll
        for (int ni = 0; ni < 7; ++ni) {
            acc[0][ni] = __builtin_amdgcn_mfma_f32_16x16x32_bf16(a0, w[ni], acc[0][ni], 0, 0, 0);
            acc[1][ni] = __builtin_amdgcn_mfma_f32_16x16x32_bf16(a1, w[ni], acc[1][ni], 0, 0, 0);
        }
        a0 = na0; a1 = na1;
        #pragma unroll
        for (int ni = 0; ni < 7; ++ni) w[ni] = nw[ni];
    }
}

// ---- GEMM pass, A from LDS bf16 buffer. ----
template<int KT, int NF>
__device__ __forceinline__ void pass_la(f32x4 (&acc)[2][8],
    const short* __restrict__ l0, const short* __restrict__ l1,
    const short* __restrict__ wp, int Kpad, int nbase, int lg)
{
    const int kb = lg * 8;
    short8 a0 = lda_l(l0 + kb);
    short8 a1 = lda_l(l1 + kb);
    short8 w[NF];
    #pragma unroll
    for (int ni = 0; ni < NF; ++ni) w[ni] = ldw_g(wp, Kpad, nbase + ni * 16, kb);
    #pragma unroll 1
    for (int t = 0; t < KT; ++t) {
        const int kn = (t + 1) * 32 + kb;
        const int kw = (t + 1 < KT) ? kn : 0;
        short8 na0 = lda_l(l0 + kw);
        short8 na1 = lda_l(l1 + kw);
        short8 nw[NF];
        #pragma unroll
        for (int ni = 0; ni < NF; ++ni) nw[ni] = ldw_g(wp, Kpad, nbase + ni * 16, kw);
        #pragma unroll
        for (int ni = 0; ni < NF; ++ni) {
            acc[0][ni] = __builtin_amdgcn_mfma_f32_16x16x32_bf16(a0, w[ni], acc[0][ni], 0, 0, 0);
            acc[1][ni] = __builtin_amdgcn_mfma_f32_16x16x32_bf16(a1, w[ni], acc[1][ni], 0, 0, 0);
        }
        a0 = na0; a1 = na1;
        #pragma unroll
        for (int ni = 0; ni < NF; ++ni) w[ni] = nw[ni];
    }
}

#define ZERO_ACC()  { _Pragma("unroll") for (int mi_=0; mi_<2; ++mi_) { _Pragma("unroll") for (int ni_=0; ni_<8; ++ni_) { _Pragma("unroll") for (int q_=0;q_<4;++q_) acc[mi_][ni_][q_] = 0.0f; } } }

__global__ __launch_bounds__(256, 2)
void fused_v2(const int* __restrict__ tok,
              const float* __restrict__ chc,
              const float* __restrict__ chh,
              const float* __restrict__ emb,
              const float* __restrict__ p1b_, const float* __restrict__ p2b_,
              const float* __restrict__ ixb, const float* __restrict__ ihb,
              const float* __restrict__ fxb, const float* __restrict__ fhb,
              const float* __restrict__ uxb, const float* __restrict__ uhb,
              const float* __restrict__ oxb, const float* __restrict__ ohb,
              const float* __restrict__ fc2b,
              const short* __restrict__ ws,
              float* __restrict__ out)
{
    __shared__ __align__(16) short SH[SH_TOT];
    short* bufA = SH;                  // control -> h
    short* bufB = SH + 64 * XP;        // hs
    short* bufX = SH + 2 * 64 * XP;    // x = emb[tok]

    const int tid = threadIdx.x;
    const int wv = tid >> 6, wm = wv >> 1, wn = wv & 1;
    const int l6 = tid & 63, l15 = tid & 15, lg = l6 >> 4;
    const int row0 = blockIdx.x * 64;
    const int nb7 = wn * 112 + l15;    // W row base, NF=7 passes
    const int nb8 = wn * 128 + l15;    // W row base, FC2

    // ---- zero entire LDS arena (pads + anything readable-before-write), then sync ----
    {
        short8 z = (short8)0;
        short8* shv = (short8*)SH;
        for (int i = tid; i < SH_TOT / 8; i += 256) shv[i] = z;
    }
    __syncthreads();   // B0: LDS zeroed before any activation writes/reads

    // clamped global rows for the two A fragments (MFMA A rows use l15)
    long rA0 = row0 + wm * 32 + l15;      if (rA0 >= NNODES) rA0 = NNODES - 1;
    long rA1 = row0 + wm * 32 + 16 + l15; if (rA1 >= NNODES) rA1 = NNODES - 1;
    const float* chh0 = chh + rA0 * 800;
    const float* chh1 = chh + rA1 * 800;

    // LDS A-row pointers
    const short* x0 = bufX + (wm * 32 + l15) * XP;
    const short* x1 = x0 + 16 * XP;
    const short* hA0 = bufA + (wm * 32 + l15) * XP;
    const short* hA1 = hA0 + 16 * XP;
    const short* hB0 = bufB + (wm * 32 + l15) * XP;
    const short* hB1 = hB0 + 16 * XP;

    // ---- x init: gather emb[tok] -> bufX (wn twins write identical data) ----
    {
        const int r = wm * 32 + (l6 >> 1);
        const int half = l6 & 1;
        long rg = row0 + r; if (rg >= NNODES) rg = NNODES - 1;
        const float* er = emb + (long)tok[rg] * DDIM + half * 100;
        short* xd = bufX + r * XP + half * 100;
        #pragma unroll 1
        for (int i = 0; i < 100; i += 4) {
            float4 f = *(const float4*)(er + i);
            unsigned u0 = cvtpk(f.x, f.y), u1 = cvtpk(f.z, f.w);
            short4v s;
            s[0] = (short)(u0 & 0xffffu); s[1] = (short)(u0 >> 16);
            s[2] = (short)(u1 & 0xffffu); s[3] = (short)(u1 >> 16);
            *(short4v*)(xd + i) = s;
        }
    }

    f32x4 acc[2][8];

    // ==== P1: control = relu([ch0|ch1|ch2] @ p1^T + b) -> bufA ====
    ZERO_ACC();
    pass_ga<19>(acc, chh0, chh1, 600, ws + W_P1, 608, nb7, lg);
    #pragma unroll
    for (int mi = 0; mi < 2; ++mi)
        #pragma unroll
        for (int ni = 0; ni < 7; ++ni) {
            const int col = (wn * 7 + ni) * 16 + l15;
            if (col < DDIM) {
                const float b = p1b_[col];
                #pragma unroll
                for (int j = 0; j < 4; ++j) {
                    const int lr = wm * 32 + mi * 16 + lg * 4 + j;
                    bufA[lr * XP + col] = f2b1(fmaxf(acc[mi][ni][j] + b, 0.0f));
                }
            }
        }
    __syncthreads();   // B1: control visible to all waves

    // ==== P2: hs = relu([control|ch3] @ p2^T + b) -> bufB ====
    ZERO_ACC();
    pass_la<7, 7>(acc, hA0, hA1, ws + W_P2A, 224, nb7, lg);
    pass_ga<7>(acc, chh0 + 600, chh1 + 600, 200, ws + W_P2B, 224, nb7, lg);
    #pragma unroll
    for (int mi = 0; mi < 2; ++mi)
        #pragma unroll
        for (int ni = 0; ni < 7; ++ni) {
            const int col = (wn * 7 + ni) * 16 + l15;
            if (col < DDIM) {
                const float b = p2b_[col];
                #pragma unroll
                for (int j = 0; j < 4; ++j) {
                    const int lr = wm * 32 + mi * 16 + lg * 4 + j;
                    bufB[lr * XP + col] = f2b1(fmaxf(acc[mi][ni][j] + b, 0.0f));
                }
            }
        }
    __syncthreads();   // B2: hs visible to all waves

    // ==== FX: fxr = x @ fx^T + b  (bf16-packed in regs) ====
    unsigned fxr_pk[2][7][2];
    ZERO_ACC();
    pass_la<7, 7>(acc, x0, x1, ws + W_FX, 224, nb7, lg);
    #pragma unroll
    for (int mi = 0; mi < 2; ++mi)
        #pragma unroll
        for (int ni = 0; ni < 7; ++ni) {
            const int col = (wn * 7 + ni) * 16 + l15;
            const float b = (col < DDIM) ? fxb[col] : 0.0f;
            fxr_pk[mi][ni][0] = cvtpk(acc[mi][ni][0] + b, acc[mi][ni][1] + b);
            fxr_pk[mi][ni][1] = cvtpk(acc[mi][ni][2] + b, acc[mi][ni][3] + b);
        }

    // ==== FH x4: csum = sum_c sigmoid(ch_c@fh^T + fhb + fx) * child_c ====
    float csum[2][7][4];
    #pragma unroll
    for (int mi = 0; mi < 2; ++mi)
        #pragma unroll
        for (int ni = 0; ni < 7; ++ni)
            #pragma unroll
            for (int j = 0; j < 4; ++j) csum[mi][ni][j] = 0.0f;

    #pragma unroll 1
    for (int c = 0; c < 4; ++c) {
        ZERO_ACC();
        pass_ga<7>(acc, chh0 + c * 200, chh1 + c * 200, 200, ws + W_FH, 224, nb7, lg);
        #pragma unroll
        for (int mi = 0; mi < 2; ++mi)
            #pragma unroll
            for (int ni = 0; ni < 7; ++ni) {
                const int col = (wn * 7 + ni) * 16 + l15;
                if (col < DDIM) {
                    const float fb = fhb[col];
                    #pragma unroll
                    for (int j = 0; j < 4; ++j) {
                        long rg = row0 + wm * 32 + mi * 16 + lg * 4 + j;
                        if (rg >= NNODES) rg = NNODES - 1;
                        const float cv = chc[rg * 800 + c * 200 + col];
                        const unsigned pk = fxr_pk[mi][ni][j >> 1];
                        const float fx = (j & 1) ? b2f_hi(pk) : b2f_lo(pk);
                        csum[mi][ni][j] += sgm(acc[mi][ni][j] + fb + fx) * cv;
                    }
                }
            }
    }

    // ==== I gate (bf16-packed) ====
    unsigned gi_pk[2][7][2];
    ZERO_ACC();
    pass_la<7, 7>(acc, x0, x1, ws + W_IX, 224, nb7, lg);
    pass_la<7, 7>(acc, hB0, hB1, ws + W_IH, 224, nb7, lg);
    #pragma unroll
    for (int mi = 0; mi < 2; ++mi)
        #pragma unroll
        for (int ni = 0; ni < 7; ++ni) {
            const int col = (wn * 7 + ni) * 16 + l15;
            const float b = (col < DDIM) ? (ixb[col] + ihb[col]) : 0.0f;
            gi_pk[mi][ni][0] = cvtpk(sgm(acc[mi][ni][0] + b), sgm(acc[mi][ni][1] + b));
            gi_pk[mi][ni][1] = cvtpk(sgm(acc[mi][ni][2] + b), sgm(acc[mi][ni][3] + b));
        }

    // ==== U gate: csum <- i*tanh(u) + csum  (= c value) ====
    ZERO_ACC();
    pass_la<7, 7>(acc, x0, x1, ws + W_UX, 224, nb7, lg);
    pass_la<7, 7>(acc, hB0, hB1, ws + W_UH, 224, nb7, lg);
    #pragma unroll
    for (int mi = 0; mi < 2; ++mi)
        #pragma unroll
        for (int ni = 0; ni < 7; ++ni) {
            const int col = (wn * 7 + ni) * 16 + l15;
            const float b = (col < DDIM) ? (uxb[col] + uhb[col]) : 0.0f;
            #pragma unroll
            for (int j = 0; j < 4; ++j) {
                const unsigned pk = gi_pk[mi][ni][j >> 1];
                const float gi = (j & 1) ? b2f_hi(pk) : b2f_lo(pk);
                csum[mi][ni][j] = gi * tanh_fast(acc[mi][ni][j] + b) + csum[mi][ni][j];
            }
        }

    // ==== O gate; h = sigmoid(o)*tanh(c) -> bufA ====
    ZERO_ACC();
    pass_la<7, 7>(acc, x0, x1, ws + W_OX, 224, nb7, lg);
    pass_la<7, 7>(acc, hB0, hB1, ws + W_OH, 224, nb7, lg);
    __syncthreads();   // all control/hs reads of bufA done before overwrite
    #pragma unroll
    for (int mi = 0; mi < 2; ++mi)
        #pragma unroll
        for (int ni = 0; ni < 7; ++ni) {
            const int col = (wn * 7 + ni) * 16 + l15;
            if (col < DDIM) {
                const float b = oxb[col] + ohb[col];
                #pragma unroll
                for (int j = 0; j < 4; ++j) {
                    const int lr = wm * 32 + mi * 16 + lg * 4 + j;
                    const float h = sgm(acc[mi][ni][j] + b) * tanh_fast(csum[mi][ni][j]);
                    bufA[lr * XP + col] = f2b1(h);
                }
            }
        }
    __syncthreads();   // B3: h visible to all waves

    // ==== FC2: logits = h @ fc2^T + b -> out ====
    ZERO_ACC();
    pass_la<7, 8>(acc, hA0, hA1, ws + W_FC2, 224, nb8, lg);
    #pragma unroll
    for (int mi = 0; mi < 2; ++mi)
        #pragma unroll
        for (int ni = 0; ni < 8; ++ni) {
            const int col = (wn * 8 + ni) * 16 + l15;
            if (col < NCLS) {
                const float b = fc2b[col];
                #pragma unroll
                for (int j = 0; j < 4; ++j) {
                    const long gr = row0 + wm * 32 + mi * 16 + lg * 4 + j;
                    if (gr < NNODES) out[gr * NCLS + col] = acc[mi][ni][j] + b;
                }
            }
        }
}

// ================= fallback fp32 kernel (used only if ws too small) =================
constexpr int FRT = 32, FBK = 16, FNT = 256, FRTP = FRT + 4, FBUFP = 208;
__device__ __forceinline__ float sgm_f(float x) { return 1.0f / (1.0f + expf(-x)); }

__device__ __forceinline__ void f_stage(
    float (*aT)[FRTP], float (*wt)[FNT], int row0, int k0,
    const float* a1g, int a1pitch, const int* gidx, const float* a1l, int a1lp, int K1,
    const float* a2g, int a2pitch, const float* a2l, int a2lp, int K2,
    const float* wa, int wap, int KW1, const float* wb, int wbp,
    int ncols, int tid)
{
    const int Ktot = K1 + K2;
    {
        const int kk = tid & 15, k = k0 + kk;
        #pragma unroll
        for (int h = 0; h < 2; ++h) {
            const int r = (tid >> 4) + h * 16;
            float v = 0.0f;
            if (k < K1) {
                if (a1l) v = a1l[r * a1lp + k];
                else {
                    const long rb = gidx ? (long)gidx[row0 + r] * a1pitch : (long)(row0 + r) * a1pitch;
                    v = a1g[rb + k];
                }
            } else if (k < Ktot) {
                if (a2l) v = a2l[r * a2lp + (k - K1)];
                else     v = a2g[(long)(row0 + r) * a2pitch + (k - K1)];
            }
            aT[kk][r] = v;
        }
    }
    {
        const int col = tid;
        #pragma unroll
        for (int kk = 0; kk < FBK; ++kk) {
            const int k = k0 + kk; float v = 0.0f;
            if (col < ncols && k < Ktot) {
                if (k < KW1) v = wa[(long)col * wap + k];
                else         v = wb[(long)col * wbp + (k - KW1)];
            }
            wt[kk][col] = v;
        }
    }
}
__device__ __forceinline__ void f_gemm(
    float (*aT)[FRTP], float (*wt)[FNT], float acc[8][4], int row0,
    const float* a1g, int a1p, const int* gidx, const float* a1l, int a1lp, int K1,
    const float* a2g, int a2p, const float* a2l, int a2lp, int K2,
    const float* wa, int wap, int KW1, const float* wb, int wbp,
    int ncols, int tid, int tr, int tc)
{
    #pragma unroll
    for (int j = 0; j < 8; ++j)
        #pragma unroll
        for (int i = 0; i < 4; ++i) acc[j][i] = 0.0f;
    const int Ktot = K1 + K2;
    for (int k0 = 0; k0 < Ktot; k0 += FBK) {
        __syncthreads();
        f_stage(aT, wt, row0, k0, a1g, a1p, gidx, a1l, a1lp, K1, a2g, a2p, a2l, a2lp, K2,
                wa, wap, KW1, wb, wbp, ncols, tid);
        __syncthreads();
        #pragma unroll
        for (int kk = 0; kk < FBK; ++kk) {
            const float w0 = wt[kk][tc*4+0], w1 = wt[kk][tc*4+1], w2 = wt[kk][tc*4+2], w3 = wt[kk][tc*4+3];
            #pragma unroll
            for (int j = 0; j < 8; ++j) {
                const float a = aT[kk][tr*8+j];
                acc[j][0] = fmaf(a, w0, acc[j][0]); acc[j][1] = fmaf(a, w1, acc[j][1]);
                acc[j][2] = fmaf(a, w2, acc[j][2]); acc[j][3] = fmaf(a, w3, acc[j][3]);
            }
        }
    }
}
__global__ __launch_bounds__(256)
void fused_fp32(const int* tok, const float* chc, const float* chh, const float* emb,
                const float* p1w, const float* p1b, const float* p2w, const float* p2b,
                const float* ixw, const float* ixb, const float* ihw, const float* ihb,
                const float* fxw, const float* fxb, const float* fhw, const float* fhb,
                const float* uxw, const float* uxb, const float* uhw, const float* uhb,
                const float* oxw, const float* oxb, const float* ohw, const float* ohb,
                const float* fc2w, const float* fc2b, float* out)
{
    __shared__ float aT[FBK][FRTP]; __shared__ float wt[FBK][FNT]; __shared__ float buf[FRT][FBUFP];
    const int tid = threadIdx.x, tr = tid >> 6, tc = tid & 63, c0 = tc * 4;
    const int row0 = blockIdx.x * FRT;
    float acc[8][4];
    f_gemm(aT, wt, acc, row0, chh, 800, nullptr, nullptr, 0, 600, nullptr,0,nullptr,0,0, p1w,600,600,nullptr,0, DDIM, tid,tr,tc);
    if (c0 < DDIM) { const float4 b = *(const float4*)&p1b[c0];
        #pragma unroll
        for (int j=0;j<8;++j){int r=tr*8+j; buf[r][c0]=fmaxf(acc[j][0]+b.x,0.f); buf[r][c0+1]=fmaxf(acc[j][1]+b.y,0.f); buf[r][c0+2]=fmaxf(acc[j][2]+b.z,0.f); buf[r][c0+3]=fmaxf(acc[j][3]+b.w,0.f);} }
    f_gemm(aT, wt, acc, row0, nullptr,0,nullptr,&buf[0][0],FBUFP,200, chh+600,800,nullptr,0,200, p2w,400,400,nullptr,0, DDIM, tid,tr,tc);
    if (c0 < DDIM) { const float4 b = *(const float4*)&p2b[c0];
        #pragma unroll
        for (int j=0;j<8;++j){int r=tr*8+j; buf[r][c0]=fmaxf(acc[j][0]+b.x,0.f); buf[r][c0+1]=fmaxf(acc[j][1]+b.y,0.f); buf[r][c0+2]=fmaxf(acc[j][2]+b.z,0.f); buf[r][c0+3]=fmaxf(acc[j][3]+b.w,0.f);} }
    f_gemm(aT, wt, acc, row0, emb, DDIM, tok, nullptr,0,200, nullptr,0,nullptr,0,0, fxw,200,200,nullptr,0, DDIM, tid,tr,tc);
    float fxr[8][4];
    { float4 b = make_float4(0,0,0,0); if (c0<DDIM) b = *(const float4*)&fxb[c0];
      #pragma unroll
      for (int j=0;j<8;++j){fxr[j][0]=acc[j][0]+b.x;fxr[j][1]=acc[j][1]+b.y;fxr[j][2]=acc[j][2]+b.z;fxr[j][3]=acc[j][3]+b.w;} }
    float csum[8][4];
    #pragma unroll
    for (int j=0;j<8;++j)
        #pragma unroll
        for (int i=0;i<4;++i) csum[j][i]=0.f;
    for (int cc_=0; cc_<4; ++cc_) {
        f_gemm(aT, wt, acc, row0, chh+cc_*200,800,nullptr,nullptr,0,200, nullptr,0,nullptr,0,0, fhw,200,200,nullptr,0, DDIM, tid,tr,tc);
        if (c0 < DDIM) { const float4 b = *(const float4*)&fhb[c0];
            #pragma unroll
            for (int j=0;j<8;++j){ const long r=row0+tr*8+j; const float4 cv=*(const float4*)&chc[r*800+cc_*200+c0];
                csum[j][0]+=sgm_f(acc[j][0]+b.x+fxr[j][0])*cv.x; csum[j][1]+=sgm_f(acc[j][1]+b.y+fxr[j][1])*cv.y;
                csum[j][2]+=sgm_f(acc[j][2]+b.z+fxr[j][2])*cv.z; csum[j][3]+=sgm_f(acc[j][3]+b.w+fxr[j][3])*cv.w; } }
    }
    f_gemm(aT, wt, acc, row0, emb, DDIM, tok, nullptr,0,200, nullptr,0,&buf[0][0],FBUFP,200, ixw,200,200,ihw,200, DDIM, tid,tr,tc);
    float gi[8][4];
    { float4 b1=make_float4(0,0,0,0),b2=b1; if(c0<DDIM){b1=*(const float4*)&ixb[c0];b2=*(const float4*)&ihb[c0];}
      #pragma unroll
      for(int j=0;j<8;++j){gi[j][0]=sgm_f(acc[j][0]+b1.x+b2.x);gi[j][1]=sgm_f(acc[j][1]+b1.y+b2.y);gi[j][2]=sgm_f(acc[j][2]+b1.z+b2.z);gi[j][3]=sgm_f(acc[j][3]+b1.w+b2.w);} }
    f_gemm(aT, wt, acc, row0, emb, DDIM, tok, nullptr,0,200, nullptr,0,&buf[0][0],FBUFP,200, uxw,200,200,uhw,200, DDIM, tid,tr,tc);
    float cval[8][4];
    { float4 b1=make_float4(0,0,0,0),b2=b1; if(c0<DDIM){b1=*(const float4*)&uxb[c0];b2=*(const float4*)&uhb[c0];}
      #pragma unroll
      for(int j=0;j<8;++j){cval[j][0]=gi[j][0]*tanhf(acc[j][0]+b1.x+b2.x)+csum[j][0];cval[j][1]=gi[j][1]*tanhf(acc[j][1]+b1.y+b2.y)+csum[j][1];
                           cval[j][2]=gi[j][2]*tanhf(acc[j][2]+b1.z+b2.z)+csum[j][2];cval[j][3]=gi[j][3]*tanhf(acc[j][3]+b1.w+b2.w)+csum[j][3];} }
    f_gemm(aT, wt, acc, row0, emb, DDIM, tok, nullptr,0,200, nullptr,0,&buf[0][0],FBUFP,200, oxw,200,200,ohw,200, DDIM, tid,tr,tc);
    if (c0 < DDIM) { const float4 b1=*(const float4*)&oxb[c0], b2=*(const float4*)&ohb[c0];
        #pragma unroll
        for(int j=0;j<8;++j){int r=tr*8+j;
            buf[r][c0]=sgm_f(acc[j][0]+b1.x+b2.x)*tanhf(cval[j][0]); buf[r][c0+1]=sgm_f(acc[j][1]+b1.y+b2.y)*tanhf(cval[j][1]);
            buf[r][c0+2]=sgm_f(acc[j][2]+b1.z+b2.z)*tanhf(cval[j][2]); buf[r][c0+3]=sgm_f(acc[j][3]+b1.w+b2.w)*tanhf(cval[j][3]);} }
    f_gemm(aT, wt, acc, row0, nullptr,0,nullptr,&buf[0][0],FBUFP,200, nullptr,0,nullptr,0,0, fc2w,200,200,nullptr,0, NCLS, tid,tr,tc);
    #pragma unroll
    for (int j=0;j<8;++j){ const long r=row0+tr*8+j;
        #pragma unroll
        for (int i=0;i<4;++i){ const int col=c0+i; if (col<NCLS) out[r*NCLS+col]=acc[j][i]+fc2b[col]; } }
}

// ================= launch =================
extern "C" void kernel_launch(void* const* d_in, const int* in_sizes, int n_in,
                              void* d_out, int out_size, void* d_ws, size_t ws_size,
                              hipStream_t stream)
{
    const int*   tok  = (const int*)  d_in[0];
    const float* chc  = (const float*)d_in[1];
    const float* chh  = (const float*)d_in[2];
    const float* emb  = (const float*)d_in[3];
    const float* p1w  = (const float*)d_in[4];
    const float* p1b  = (const float*)d_in[5];
    const float* p2w  = (const float*)d_in[6];
    const float* p2b  = (const float*)d_in[7];
    const float* ixw  = (const float*)d_in[8];
    const float* ixb  = (const float*)d_in[9];
    const float* ihw  = (const float*)d_in[10];
    const float* ihb  = (const float*)d_in[11];
    const float* fxw  = (const float*)d_in[12];
    const float* fxb  = (const float*)d_in[13];
    const float* fhw  = (const float*)d_in[14];
    const float* fhb  = (const float*)d_in[15];
    const float* uxw  = (const float*)d_in[16];
    const float* uxb  = (const float*)d_in[17];
    const float* uhw  = (const float*)d_in[18];
    const float* uhb  = (const float*)d_in[19];
    const float* oxw  = (const float*)d_in[20];
    const float* oxb  = (const float*)d_in[21];
    const float* ohw  = (const float*)d_in[22];
    const float* ohb  = (const float*)d_in[23];
    const float* fc2w = (const float*)d_in[24];
    const float* fc2b = (const float*)d_in[25];
    float* out = (float*)d_out;

    if (ws_size >= W_TOTAL_BYTES) {
        short* ws = (short*)d_ws;
        hipLaunchKernelGGL(wprep, dim3((W_TOTAL_ELEMS + 255) / 256), dim3(256), 0, stream,
                           p1w, p2w, fxw, fhw, ixw, ihw, uxw, uhw, oxw, ohw, fc2w, ws);
        hipLaunchKernelGGL(fused_v2, dim3((NNODES + 63) / 64), dim3(256), 0, stream,
                           tok, chc, chh, emb,
                           p1b, p2b, ixb, ihb, fxb, fhb, uxb, uhb, oxb, ohb, fc2b,
                           ws, out);
    } else {
        hipLaunchKernelGGL(fused_fp32, dim3(NNODES / FRT), dim3(256), 0, stream,
                           tok, chc, chh, emb, p1w, p1b, p2w, p2b,
                           ixw, ixb, ihw, ihb, fxw, fxb, fhw, fhb,
                           uxw, uxb, uhw, uhb, oxw, oxb, ohw, ohb, fc2w, fc2b, out);
    }
}